// Round 10
// baseline (160.156 us; speedup 1.0000x reference)
//
#include <hip/hip_runtime.h>
#include <hip/hip_bf16.h>

#define S_DIM 128
#define N_DIM 256
#define CIN   256
#define CH    32
#define COUT  128

typedef __attribute__((ext_vector_type(8))) short bf16x8;
typedef __attribute__((ext_vector_type(4))) float f32x4;
typedef __attribute__((ext_vector_type(16))) float f32x16;

__device__ __forceinline__ unsigned short f2bf(float f) {
  union { float f; unsigned int u; } v; v.f = f;
  unsigned int u = v.u;
  return (unsigned short)((u + 0x7FFFu + ((u >> 16) & 1u)) >> 16);
}

// packed f32x2 -> bf16x2 (RNE, bit-identical to f2bf pairs)
__device__ __forceinline__ unsigned int pk2(float x, float y) {
  float2 f2; f2.x = x; f2.y = y;
  __hip_bfloat162 h = __float22bfloat162_rn(f2);
  union { __hip_bfloat162 h; unsigned int u; } c; c.h = h;
  return c.u;
}

// ---------------------------------------------------------------------------
// Front-end v2 (R5/R8-verified): merged LN+projection and prep, packed cvt +
// hoisted row loads. wo3 pack: 32x32x16 B-frag layout (R8 verbatim — R9's
// 16x16 pack reverted with the fused revert).
//   blocks 0..1023   : LayerNorm + MFMA projection (wab in LDS)
//   blocks 1024..1151: wo3 = Wo bf16 packed for 32x32x16 B-frags
//   blocks 1152..1407: rnm = 1 / clip(mask^T mask, 1)
// ---------------------------------------------------------------------------
__global__ __launch_bounds__(256) void lnp_prep_kernel(
    const float* __restrict__ m, const float* __restrict__ mask,
    const float* __restrict__ gamma, const float* __restrict__ beta,
    const float* __restrict__ Wa, const float* __restrict__ Wb,
    const float* __restrict__ Wo,
    float* __restrict__ rnm, unsigned short* __restrict__ wo3,
    unsigned short* __restrict__ a_t, unsigned short* __restrict__ b_t) {
  const int b = blockIdx.x, t = threadIdx.x;
  if (b < 1024) {
    __shared__ __align__(16) unsigned short mn[32][264];   // +8 pad
    __shared__ __align__(16) unsigned short wabs[64 * 256];
    const int i = b & 255, s0 = (b >> 8) * 32;
    const int w = t >> 6, l = t & 63, lq = l >> 4, lr = l & 15;

    // Wa/Wb -> wabs, granule-swizzled: g' = (g&16)|((g ^ (r&15))&15)
    #pragma unroll
    for (int it = 0; it < 8; it++) {
      const int gi = it * 256 + t;       // granule 0..2047 (64 rows x 32)
      const int r = gi >> 5, g = gi & 31;
      const float* src = (r < 32) ? (Wa + r * 256 + g * 8)
                                  : (Wb + (r - 32) * 256 + g * 8);
      const int gp = (g & 16) | ((g ^ (r & 15)) & 15);
      const float4 v0 = *(const float4*)(src);
      const float4 v1 = *(const float4*)(src + 4);
      uint4 qv;
      qv.x = pk2(v0.x, v0.y); qv.y = pk2(v0.z, v0.w);
      qv.z = pk2(v1.x, v1.y); qv.w = pk2(v1.z, v1.w);
      *(uint4*)(&wabs[r * 256 + gp * 8]) = qv;
    }

    const float4 g4 = *(const float4*)(gamma + l * 4);
    const float4 b4 = *(const float4*)(beta + l * 4);

    // hoist all row loads (one latency exposure)
    float4 mv[8];
    float mkv[8];
    #pragma unroll
    for (int rr = 0; rr < 8; rr++) {
      const int s = s0 + w * 8 + rr;
      mv[rr] = *(const float4*)(m + ((size_t)(s * N_DIM + i)) * CIN + l * 4);
      mkv[rr] = mask[s * N_DIM + i];
    }

    #pragma unroll
    for (int rr = 0; rr < 8; rr++) {
      const int r = w * 8 + rr;
      const float4 v = mv[rr];
      float sum = v.x + v.y + v.z + v.w;
      float sq  = v.x * v.x + v.y * v.y + v.z * v.z + v.w * v.w;
      #pragma unroll
      for (int off = 32; off > 0; off >>= 1) {
        sum += __shfl_down(sum, off);
        sq  += __shfl_down(sq, off);
      }
      sum = __shfl(sum, 0); sq = __shfl(sq, 0);
      const float mu = sum * (1.0f / CIN);
      const float var = fmaxf(sq * (1.0f / CIN) - mu * mu, 0.0f);
      const float rs = rsqrtf(var + 1e-5f);
      const float mk = mkv[rr];
      uint2 p2;
      p2.x = pk2(((v.x - mu) * rs * g4.x + b4.x) * mk,
                 ((v.y - mu) * rs * g4.y + b4.y) * mk);
      p2.y = pk2(((v.z - mu) * rs * g4.z + b4.z) * mk,
                 ((v.w - mu) * rs * g4.w + b4.w) * mk);
      *(uint2*)(&mn[r][l * 4]) = p2;
    }
    __syncthreads();

    // MFMA: M=32 s-rows, N=64 [Wa|Wb], K=256
    const int wm = w & 1;
    const int n2 = w >> 1;
    f32x4 acc0 = {0.f, 0.f, 0.f, 0.f}, acc1 = {0.f, 0.f, 0.f, 0.f};
    #pragma unroll
    for (int ks = 0; ks < 8; ks++) {
      const int k0 = ks * 32 + lq * 8;
      const int g = ks * 4 + lq;
      const int gp = (g & 16) | ((g ^ lr) & 15);
      const bf16x8 af = *(const bf16x8*)(&mn[wm * 16 + lr][k0]);
      const bf16x8 bf0 = *(const bf16x8*)(&wabs[(n2 * 32 + lr) * 256 + gp * 8]);
      const bf16x8 bf1 = *(const bf16x8*)(&wabs[(n2 * 32 + 16 + lr) * 256 + gp * 8]);
      acc0 = __builtin_amdgcn_mfma_f32_16x16x32_bf16(af, bf0, acc0, 0, 0, 0);
      acc1 = __builtin_amdgcn_mfma_f32_16x16x32_bf16(af, bf1, acc1, 0, 0, 0);
    }

    unsigned short* dst = (n2 == 0) ? a_t : b_t;
    const int scol = s0 + wm * 16 + lq * 4;
    uint2 q0, q1;
    q0.x = pk2(acc0[0], acc0[1]); q0.y = pk2(acc0[2], acc0[3]);
    q1.x = pk2(acc1[0], acc1[1]); q1.y = pk2(acc1[2], acc1[3]);
    *(uint2*)(dst + ((size_t)(i * CH + lr)) * S_DIM + scol) = q0;
    *(uint2*)(dst + ((size_t)(i * CH + 16 + lr)) * S_DIM + scol) = q1;
  } else if (b < 1152) {
    const int r = b - 1024;  // 0..127
    // 32x32x16 B-frag pack (R8 layout): n = o = og*32+(l&31),
    // k' = step*16 + (l>>5)*8 + e, c = k'&31, d = k'>>5.
    #pragma unroll
    for (int q = 0; q < 4; q++) {
      const int f = r * 1024 + q * 256 + t;        // 0..131071
      const int e = f & 7, l = (f >> 3) & 63;
      const int step = (f >> 9) & 63, og = f >> 15;
      const int kp = step * 16 + (l >> 5) * 8 + e;
      const int c = kp & 31, d = kp >> 5;
      const int o = og * 32 + (l & 31);
      wo3[f] = f2bf(Wo[o * 1024 + c * 32 + d]);
    }
  } else {
    const int i = b - 1152;  // 0..255
    float acc = 0.f;
    #pragma unroll 8
    for (int s = 0; s < S_DIM; s++)
      acc += mask[s * N_DIM + i] * mask[s * N_DIM + t];
    acc = fmaxf(acc, 1.0f);
    rnm[i * N_DIM + t] = 1.0f / acc;
  }
}

// ---------------------------------------------------------------------------
// fused v15: exact R8/v13 revert (best verified: 46.9 us) + s_setprio(1)
// around the GEMM2 MFMA clusters (T5). R9's 16x16 GEMM2 regressed (bank
// conflicts 3.15M -> 5.24M, zf traffic doubled) — reverted wholesale.
// T5 rationale: 2 co-resident blocks run phase-offset; during this block's
// GEMM2 (1 wave/SIMD), the other block's GEMM1/stage waves compete for
// issue; setprio biases the SIMD toward the MFMA-issuing wave.
// ---------------------------------------------------------------------------
__global__ __launch_bounds__(512, 4) void fused_kernel(
    const unsigned short* __restrict__ a_t, const unsigned short* __restrict__ b_t,
    const unsigned short* __restrict__ wo3, const float* __restrict__ rnm,
    const float* __restrict__ bo, float* __restrict__ out) {
  extern __shared__ __align__(16) unsigned short smem[];
  unsigned short* sA = smem;            // 256 x 64 ushort = 32 KB
  unsigned short* sB = smem + 16384;    // 128 x 64 ushort = 16 KB
  unsigned short* sZ = smem;            // 32 pairs x 1024 ushort = 64 KB overlay

  const int t = threadIdx.x, w = t >> 6, l = t & 63;
  const int lq = l >> 4, lr = l & 15;
  const int bx = blockIdx.x, by = blockIdx.y;

  const unsigned short* srcA = a_t + (size_t)bx * 32768;   // 8 i x 32 c x 128 s
  const unsigned short* srcB = b_t + (size_t)by * 16384;   // 4 j x 32 d x 128 s

  // GEMM2 wave job: waves 0..3 own o-group w, full K. (w>=4: idle in GEMM2.)
  const int og = w & 3;
  const int pA = l & 31;
  const unsigned short* wop = wo3 + ((size_t)(og * 64) * 64 + l) * 8;

  // GEMM1: wave (wy, wx) owns 64x64 of the 256x128 product
  const int wy = (w >> 1) * 64, wx = (w & 1) * 64;
  f32x4 acc[4][4];
  #pragma unroll
  for (int a = 0; a < 4; a++)
    #pragma unroll
    for (int c = 0; c < 4; c++) acc[a][c] = (f32x4){0.f, 0.f, 0.f, 0.f};

  // ---- K-chunked stage + GEMM1 (chunk h covers k in [h*64, h*64+64)) ----
  #pragma unroll 1
  for (int h = 0; h < 2; h++) {
    if (h) __syncthreads();            // chunk-0 fragment reads done
    #pragma unroll
    for (int it = 0; it < 4; it++) {   // A: 2048 granules
      const int idx = it * 512 + t;
      const int r = idx >> 3, g = idx & 7;
      const bf16x8 v = *(const bf16x8*)(srcA + r * 128 + h * 64 + g * 8);
      *(bf16x8*)(&sA[r * 64 + ((g ^ (r & 7)) << 3)]) = v;
    }
    #pragma unroll
    for (int it = 0; it < 2; it++) {   // B: 1024 granules
      const int idx = it * 512 + t;
      const int r = idx >> 3, g = idx & 7;
      const bf16x8 v = *(const bf16x8*)(srcB + r * 128 + h * 64 + g * 8);
      *(bf16x8*)(&sB[r * 64 + ((g ^ (r & 7)) << 3)]) = v;
    }
    __syncthreads();

    #pragma unroll
    for (int ks2 = 0; ks2 < 2; ks2++) {
      const int gi = ks2 * 4 + lq;     // granule within chunk
      bf16x8 afr[4], bfr[4];
      #pragma unroll
      for (int a = 0; a < 4; a++) {
        const int ra = wy + a * 16 + lr;
        afr[a] = *(const bf16x8*)(&sA[ra * 64 + ((gi ^ (ra & 7)) << 3)]);
        const int rb = wx + a * 16 + lr;
        bfr[a] = *(const bf16x8*)(&sB[rb * 64 + ((gi ^ (rb & 7)) << 3)]);
      }
      #pragma unroll
      for (int a = 0; a < 4; a++)
        #pragma unroll
        for (int c = 0; c < 4; c++)
          acc[a][c] = __builtin_amdgcn_mfma_f32_16x16x32_bf16(afr[a], bfr[c], acc[a][c], 0, 0, 0);
    }
  }

  // wf batch-0 prefetch: issued before the transpose phase so the VM pipe
  // overlaps the VALU/LDS transpose work (only GEMM2 waves).
  bf16x8 wfb0[4], wfb1[4];
  if (w < 4) {
    #pragma unroll
    for (int q = 0; q < 4; q++)
      wfb0[q] = *(const bf16x8*)(wop + (size_t)q * 512);
  }

  __syncthreads();  // all GEMM1 reads done before sZ overlays sA/sB

  // ---- transpose: acc (C/D layout) -> sZ[pair][k'=d*32+c] ----
  // pair = (zrb>>5)*4 + (zc>>5); granule map gp = (g&~7)|((g^(g>>3)^pair)&7)
  #pragma unroll
  for (int a = 0; a < 4; a++) {
    #pragma unroll
    for (int c = 0; c < 4; c++) {
      const int zrb = wy + a * 16 + lq * 4;
      const int zc  = wx + c * 16 + lr;
      const int pr = (zrb >> 5) * 4 + (zc >> 5);      // 0..31
      const int off = (zc & 31) * 32 + (zrb & 31);
      const int g = off >> 3;
      const int gp = (g & ~7) | ((g ^ (g >> 3) ^ pr) & 7);
      uint2 q;
      q.x = pk2(acc[a][c][0], acc[a][c][1]);
      q.y = pk2(acc[a][c][2], acc[a][c][3]);
      *(uint2*)(&sZ[pr * 1024 + gp * 8 + (off & 7)]) = q;
    }
  }
  __syncthreads();

  if (w >= 4) return;   // GEMM1/transpose-only waves are done

  // wf batch 1 + epilogue operands (rnm/bo) — all independent of GEMM2
  #pragma unroll
  for (int q = 0; q < 4; q++)
    wfb1[q] = *(const bf16x8*)(wop + (size_t)(4 + q) * 512);

  const int o = og * 32 + (l & 31);
  const float bov = bo[o];
  float scv[16];
  #pragma unroll
  for (int r = 0; r < 16; r++) {
    const int row = (r & 3) + 8 * (r >> 2) + 4 * (l >> 5);   // pair 0..31
    const int ii = bx * 8 + (row >> 2), jj = by * 4 + (row & 3);
    scv[r] = rnm[ii * N_DIM + jj];
  }

  // ---- GEMM2: 32x32x16, M = 32 pairs, full K = 64 steps per wave ----
  f32x16 acc2;
  #pragma unroll
  for (int r = 0; r < 16; r++) acc2[r] = 0.f;

  #pragma unroll
  for (int jb = 0; jb < 16; jb++) {
    __builtin_amdgcn_s_setprio(1);             // T5: favor the MFMA wave
    #pragma unroll
    for (int q = 0; q < 4; q++) {
      const int s = jb * 4 + q;                  // global k-step (16 k each)
      const int g = s * 2 + (l >> 5);            // granule of this lane's chunk
      const int gA = (g & ~7) | ((g ^ (g >> 3) ^ pA) & 7);
      const bf16x8 zf = *(const bf16x8*)(&sZ[pA * 1024 + gA * 8]);
      const bf16x8 wf = (jb & 1) ? wfb1[q] : wfb0[q];
      acc2 = __builtin_amdgcn_mfma_f32_32x32x16_bf16(zf, wf, acc2, 0, 0, 0);
    }
    __builtin_amdgcn_s_setprio(0);
    if (jb < 14) {
      #pragma unroll
      for (int q = 0; q < 4; q++) {
        const bf16x8 v = *(const bf16x8*)(wop + (size_t)((jb + 2) * 4 + q) * 512);
        if (jb & 1) wfb1[q] = v; else wfb0[q] = v;
      }
    }
  }

  // ---- epilogue: direct from registers, 32x32 D layout ----
  #pragma unroll
  for (int r = 0; r < 16; r++) {
    const int row = (r & 3) + 8 * (r >> 2) + 4 * (l >> 5);   // pair 0..31
    const int ii = bx * 8 + (row >> 2), jj = by * 4 + (row & 3);
    out[((size_t)(ii * N_DIM + jj)) * COUT + o] = acc2[r] * scv[r] + bov;
  }
}

// ---------------------------------------------------------------------------
extern "C" void kernel_launch(void* const* d_in, const int* in_sizes, int n_in,
                              void* d_out, int out_size, void* d_ws, size_t ws_size,
                              hipStream_t stream) {
  const float* m     = (const float*)d_in[0];
  const float* mask  = (const float*)d_in[1];
  const float* gamma = (const float*)d_in[2];
  const float* beta  = (const float*)d_in[3];
  const float* Wa    = (const float*)d_in[4];
  const float* Wb    = (const float*)d_in[5];
  const float* Wo    = (const float*)d_in[6];
  const float* bo    = (const float*)d_in[7];
  float* out = (float*)d_out;

  char* ws = (char*)d_ws;
  float*          rnm = (float*)(ws);                     // 256 KB
  unsigned short* wo3 = (unsigned short*)(ws + 262144);   // 256 KB
  unsigned short* a_t = (unsigned short*)(ws + 524288);   //   2 MB
  unsigned short* b_t = (unsigned short*)(ws + 2621440);  //   2 MB

  hipFuncSetAttribute((const void*)fused_kernel,
                      hipFuncAttributeMaxDynamicSharedMemorySize, 65536);

  lnp_prep_kernel<<<1408, 256, 0, stream>>>(m, mask, gamma, beta, Wa, Wb, Wo,
                                            rnm, wo3, a_t, b_t);
  fused_kernel<<<dim3(32, 64), 512, 65536, stream>>>(a_t, b_t, wo3, rnm, bo, out);
}

// Round 11
// 139.136 us; speedup vs baseline: 1.1511x; 1.1511x over previous
//
#include <hip/hip_runtime.h>
#include <hip/hip_bf16.h>

#define S_DIM 128
#define N_DIM 256
#define CIN   256
#define CH    32
#define COUT  128

typedef __attribute__((ext_vector_type(8))) short bf16x8;
typedef __attribute__((ext_vector_type(4))) float f32x4;
typedef __attribute__((ext_vector_type(16))) float f32x16;

__device__ __forceinline__ unsigned short f2bf(float f) {
  union { float f; unsigned int u; } v; v.f = f;
  unsigned int u = v.u;
  return (unsigned short)((u + 0x7FFFu + ((u >> 16) & 1u)) >> 16);
}

// packed f32x2 -> bf16x2 (RNE, bit-identical to f2bf pairs)
__device__ __forceinline__ unsigned int pk2(float x, float y) {
  float2 f2; f2.x = x; f2.y = y;
  __hip_bfloat162 h = __float22bfloat162_rn(f2);
  union { __hip_bfloat162 h; unsigned int u; } c; c.h = h;
  return c.u;
}

// ---------------------------------------------------------------------------
// Front-end v2 (R5/R8-verified): merged LN+projection and prep, packed cvt +
// hoisted row loads.
//   blocks 0..1023   : LayerNorm + MFMA projection (wab in LDS)
//   blocks 1024..1151: wo3 = Wo bf16 packed for 32x32x16 B-frags
//   blocks 1152..1407: rnm = 1 / clip(mask^T mask, 1)
// ---------------------------------------------------------------------------
__global__ __launch_bounds__(256) void lnp_prep_kernel(
    const float* __restrict__ m, const float* __restrict__ mask,
    const float* __restrict__ gamma, const float* __restrict__ beta,
    const float* __restrict__ Wa, const float* __restrict__ Wb,
    const float* __restrict__ Wo,
    float* __restrict__ rnm, unsigned short* __restrict__ wo3,
    unsigned short* __restrict__ a_t, unsigned short* __restrict__ b_t) {
  const int b = blockIdx.x, t = threadIdx.x;
  if (b < 1024) {
    __shared__ __align__(16) unsigned short mn[32][264];   // +8 pad
    __shared__ __align__(16) unsigned short wabs[64 * 256];
    const int i = b & 255, s0 = (b >> 8) * 32;
    const int w = t >> 6, l = t & 63, lq = l >> 4, lr = l & 15;

    // Wa/Wb -> wabs, granule-swizzled: g' = (g&16)|((g ^ (r&15))&15)
    #pragma unroll
    for (int it = 0; it < 8; it++) {
      const int gi = it * 256 + t;       // granule 0..2047 (64 rows x 32)
      const int r = gi >> 5, g = gi & 31;
      const float* src = (r < 32) ? (Wa + r * 256 + g * 8)
                                  : (Wb + (r - 32) * 256 + g * 8);
      const int gp = (g & 16) | ((g ^ (r & 15)) & 15);
      const float4 v0 = *(const float4*)(src);
      const float4 v1 = *(const float4*)(src + 4);
      uint4 qv;
      qv.x = pk2(v0.x, v0.y); qv.y = pk2(v0.z, v0.w);
      qv.z = pk2(v1.x, v1.y); qv.w = pk2(v1.z, v1.w);
      *(uint4*)(&wabs[r * 256 + gp * 8]) = qv;
    }

    const float4 g4 = *(const float4*)(gamma + l * 4);
    const float4 b4 = *(const float4*)(beta + l * 4);

    // hoist all row loads (one latency exposure)
    float4 mv[8];
    float mkv[8];
    #pragma unroll
    for (int rr = 0; rr < 8; rr++) {
      const int s = s0 + w * 8 + rr;
      mv[rr] = *(const float4*)(m + ((size_t)(s * N_DIM + i)) * CIN + l * 4);
      mkv[rr] = mask[s * N_DIM + i];
    }

    #pragma unroll
    for (int rr = 0; rr < 8; rr++) {
      const int r = w * 8 + rr;
      const float4 v = mv[rr];
      float sum = v.x + v.y + v.z + v.w;
      float sq  = v.x * v.x + v.y * v.y + v.z * v.z + v.w * v.w;
      #pragma unroll
      for (int off = 32; off > 0; off >>= 1) {
        sum += __shfl_down(sum, off);
        sq  += __shfl_down(sq, off);
      }
      sum = __shfl(sum, 0); sq = __shfl(sq, 0);
      const float mu = sum * (1.0f / CIN);
      const float var = fmaxf(sq * (1.0f / CIN) - mu * mu, 0.0f);
      const float rs = rsqrtf(var + 1e-5f);
      const float mk = mkv[rr];
      uint2 p2;
      p2.x = pk2(((v.x - mu) * rs * g4.x + b4.x) * mk,
                 ((v.y - mu) * rs * g4.y + b4.y) * mk);
      p2.y = pk2(((v.z - mu) * rs * g4.z + b4.z) * mk,
                 ((v.w - mu) * rs * g4.w + b4.w) * mk);
      *(uint2*)(&mn[r][l * 4]) = p2;
    }
    __syncthreads();

    // MFMA: M=32 s-rows, N=64 [Wa|Wb], K=256
    const int wm = w & 1;
    const int n2 = w >> 1;
    f32x4 acc0 = {0.f, 0.f, 0.f, 0.f}, acc1 = {0.f, 0.f, 0.f, 0.f};
    #pragma unroll
    for (int ks = 0; ks < 8; ks++) {
      const int k0 = ks * 32 + lq * 8;
      const int g = ks * 4 + lq;
      const int gp = (g & 16) | ((g ^ lr) & 15);
      const bf16x8 af = *(const bf16x8*)(&mn[wm * 16 + lr][k0]);
      const bf16x8 bf0 = *(const bf16x8*)(&wabs[(n2 * 32 + lr) * 256 + gp * 8]);
      const bf16x8 bf1 = *(const bf16x8*)(&wabs[(n2 * 32 + 16 + lr) * 256 + gp * 8]);
      acc0 = __builtin_amdgcn_mfma_f32_16x16x32_bf16(af, bf0, acc0, 0, 0, 0);
      acc1 = __builtin_amdgcn_mfma_f32_16x16x32_bf16(af, bf1, acc1, 0, 0, 0);
    }

    unsigned short* dst = (n2 == 0) ? a_t : b_t;
    const int scol = s0 + wm * 16 + lq * 4;
    uint2 q0, q1;
    q0.x = pk2(acc0[0], acc0[1]); q0.y = pk2(acc0[2], acc0[3]);
    q1.x = pk2(acc1[0], acc1[1]); q1.y = pk2(acc1[2], acc1[3]);
    *(uint2*)(dst + ((size_t)(i * CH + lr)) * S_DIM + scol) = q0;
    *(uint2*)(dst + ((size_t)(i * CH + 16 + lr)) * S_DIM + scol) = q1;
  } else if (b < 1152) {
    const int r = b - 1024;  // 0..127
    // 32x32x16 B-frag pack (R8 layout): n = o = og*32+(l&31),
    // k' = step*16 + (l>>5)*8 + e, c = k'&31, d = k'>>5.
    #pragma unroll
    for (int q = 0; q < 4; q++) {
      const int f = r * 1024 + q * 256 + t;        // 0..131071
      const int e = f & 7, l = (f >> 3) & 63;
      const int step = (f >> 9) & 63, og = f >> 15;
      const int kp = step * 16 + (l >> 5) * 8 + e;
      const int c = kp & 31, d = kp >> 5;
      const int o = og * 32 + (l & 31);
      wo3[f] = f2bf(Wo[o * 1024 + c * 32 + d]);
    }
  } else {
    const int i = b - 1152;  // 0..255
    float acc = 0.f;
    #pragma unroll 8
    for (int s = 0; s < S_DIM; s++)
      acc += mask[s * N_DIM + i] * mask[s * N_DIM + t];
    acc = fmaxf(acc, 1.0f);
    rnm[i * N_DIM + t] = 1.0f / acc;
  }
}

// ---------------------------------------------------------------------------
// fused v13 (R8 exact revert — session best: 46.9 us fused, 140.6 total).
// R10's setprio fences inside the GEMM2 loop caused register spills
// (WRITE_SIZE 32.8 -> 63.4 MB) — removed. Structure:
//   stage  : 2x64k-chunk reg->LDS, swizzle g' = g ^ (r&7) (verified clean)
//   GEMM1  : 16x16x32, wave grid 4x2, 64x64/wave, acc[4][4]
//   transp : acc -> sZ[pair][k'=d*32+c], gp = (g&~7)|((g^(g>>3)^pair)&7)
//   GEMM2  : 32x32x16, 4 waves (og), full K=64 steps, wf double-buffered
//            reg prefetch (2 batches in flight); waves 4-7 exit
//   epilog : direct from registers via 32x32 D layout, rnm/bo hoisted
// ---------------------------------------------------------------------------
__global__ __launch_bounds__(512, 4) void fused_kernel(
    const unsigned short* __restrict__ a_t, const unsigned short* __restrict__ b_t,
    const unsigned short* __restrict__ wo3, const float* __restrict__ rnm,
    const float* __restrict__ bo, float* __restrict__ out) {
  extern __shared__ __align__(16) unsigned short smem[];
  unsigned short* sA = smem;            // 256 x 64 ushort = 32 KB
  unsigned short* sB = smem + 16384;    // 128 x 64 ushort = 16 KB
  unsigned short* sZ = smem;            // 32 pairs x 1024 ushort = 64 KB overlay

  const int t = threadIdx.x, w = t >> 6, l = t & 63;
  const int lq = l >> 4, lr = l & 15;
  const int bx = blockIdx.x, by = blockIdx.y;

  const unsigned short* srcA = a_t + (size_t)bx * 32768;   // 8 i x 32 c x 128 s
  const unsigned short* srcB = b_t + (size_t)by * 16384;   // 4 j x 32 d x 128 s

  // GEMM2 wave job: waves 0..3 own o-group w, full K. (w>=4: idle in GEMM2.)
  const int og = w & 3;
  const int pA = l & 31;
  const unsigned short* wop = wo3 + ((size_t)(og * 64) * 64 + l) * 8;

  // GEMM1: wave (wy, wx) owns 64x64 of the 256x128 product
  const int wy = (w >> 1) * 64, wx = (w & 1) * 64;
  f32x4 acc[4][4];
  #pragma unroll
  for (int a = 0; a < 4; a++)
    #pragma unroll
    for (int c = 0; c < 4; c++) acc[a][c] = (f32x4){0.f, 0.f, 0.f, 0.f};

  // ---- K-chunked stage + GEMM1 (chunk h covers k in [h*64, h*64+64)) ----
  #pragma unroll 1
  for (int h = 0; h < 2; h++) {
    if (h) __syncthreads();            // chunk-0 fragment reads done
    #pragma unroll
    for (int it = 0; it < 4; it++) {   // A: 2048 granules
      const int idx = it * 512 + t;
      const int r = idx >> 3, g = idx & 7;
      const bf16x8 v = *(const bf16x8*)(srcA + r * 128 + h * 64 + g * 8);
      *(bf16x8*)(&sA[r * 64 + ((g ^ (r & 7)) << 3)]) = v;
    }
    #pragma unroll
    for (int it = 0; it < 2; it++) {   // B: 1024 granules
      const int idx = it * 512 + t;
      const int r = idx >> 3, g = idx & 7;
      const bf16x8 v = *(const bf16x8*)(srcB + r * 128 + h * 64 + g * 8);
      *(bf16x8*)(&sB[r * 64 + ((g ^ (r & 7)) << 3)]) = v;
    }
    __syncthreads();

    #pragma unroll
    for (int ks2 = 0; ks2 < 2; ks2++) {
      const int gi = ks2 * 4 + lq;     // granule within chunk
      bf16x8 afr[4], bfr[4];
      #pragma unroll
      for (int a = 0; a < 4; a++) {
        const int ra = wy + a * 16 + lr;
        afr[a] = *(const bf16x8*)(&sA[ra * 64 + ((gi ^ (ra & 7)) << 3)]);
        const int rb = wx + a * 16 + lr;
        bfr[a] = *(const bf16x8*)(&sB[rb * 64 + ((gi ^ (rb & 7)) << 3)]);
      }
      #pragma unroll
      for (int a = 0; a < 4; a++)
        #pragma unroll
        for (int c = 0; c < 4; c++)
          acc[a][c] = __builtin_amdgcn_mfma_f32_16x16x32_bf16(afr[a], bfr[c], acc[a][c], 0, 0, 0);
    }
  }

  // wf batch-0 prefetch: issued before the transpose phase so the VM pipe
  // overlaps the VALU/LDS transpose work (only GEMM2 waves).
  bf16x8 wfb0[4], wfb1[4];
  if (w < 4) {
    #pragma unroll
    for (int q = 0; q < 4; q++)
      wfb0[q] = *(const bf16x8*)(wop + (size_t)q * 512);
  }

  __syncthreads();  // all GEMM1 reads done before sZ overlays sA/sB

  // ---- transpose: acc (C/D layout) -> sZ[pair][k'=d*32+c] ----
  // pair = (zrb>>5)*4 + (zc>>5); granule map gp = (g&~7)|((g^(g>>3)^pair)&7)
  #pragma unroll
  for (int a = 0; a < 4; a++) {
    #pragma unroll
    for (int c = 0; c < 4; c++) {
      const int zrb = wy + a * 16 + lq * 4;
      const int zc  = wx + c * 16 + lr;
      const int pr = (zrb >> 5) * 4 + (zc >> 5);      // 0..31
      const int off = (zc & 31) * 32 + (zrb & 31);
      const int g = off >> 3;
      const int gp = (g & ~7) | ((g ^ (g >> 3) ^ pr) & 7);
      uint2 q;
      q.x = pk2(acc[a][c][0], acc[a][c][1]);
      q.y = pk2(acc[a][c][2], acc[a][c][3]);
      *(uint2*)(&sZ[pr * 1024 + gp * 8 + (off & 7)]) = q;
    }
  }
  __syncthreads();

  if (w >= 4) return;   // GEMM1/transpose-only waves are done

  // wf batch 1 + epilogue operands (rnm/bo) — all independent of GEMM2
  #pragma unroll
  for (int q = 0; q < 4; q++)
    wfb1[q] = *(const bf16x8*)(wop + (size_t)(4 + q) * 512);

  const int o = og * 32 + (l & 31);
  const float bov = bo[o];
  float scv[16];
  #pragma unroll
  for (int r = 0; r < 16; r++) {
    const int row = (r & 3) + 8 * (r >> 2) + 4 * (l >> 5);   // pair 0..31
    const int ii = bx * 8 + (row >> 2), jj = by * 4 + (row & 3);
    scv[r] = rnm[ii * N_DIM + jj];
  }

  // ---- GEMM2: 32x32x16, M = 32 pairs, full K = 64 steps per wave ----
  f32x16 acc2;
  #pragma unroll
  for (int r = 0; r < 16; r++) acc2[r] = 0.f;

  #pragma unroll
  for (int jb = 0; jb < 16; jb++) {
    #pragma unroll
    for (int q = 0; q < 4; q++) {
      const int s = jb * 4 + q;                  // global k-step (16 k each)
      const int g = s * 2 + (l >> 5);            // granule of this lane's chunk
      const int gA = (g & ~7) | ((g ^ (g >> 3) ^ pA) & 7);
      const bf16x8 zf = *(const bf16x8*)(&sZ[pA * 1024 + gA * 8]);
      const bf16x8 wf = (jb & 1) ? wfb1[q] : wfb0[q];
      acc2 = __builtin_amdgcn_mfma_f32_32x32x16_bf16(zf, wf, acc2, 0, 0, 0);
    }
    if (jb < 14) {
      #pragma unroll
      for (int q = 0; q < 4; q++) {
        const bf16x8 v = *(const bf16x8*)(wop + (size_t)((jb + 2) * 4 + q) * 512);
        if (jb & 1) wfb1[q] = v; else wfb0[q] = v;
      }
    }
  }

  // ---- epilogue: direct from registers, 32x32 D layout ----
  #pragma unroll
  for (int r = 0; r < 16; r++) {
    const int row = (r & 3) + 8 * (r >> 2) + 4 * (l >> 5);   // pair 0..31
    const int ii = bx * 8 + (row >> 2), jj = by * 4 + (row & 3);
    out[((size_t)(ii * N_DIM + jj)) * COUT + o] = acc2[r] * scv[r] + bov;
  }
}

// ---------------------------------------------------------------------------
extern "C" void kernel_launch(void* const* d_in, const int* in_sizes, int n_in,
                              void* d_out, int out_size, void* d_ws, size_t ws_size,
                              hipStream_t stream) {
  const float* m     = (const float*)d_in[0];
  const float* mask  = (const float*)d_in[1];
  const float* gamma = (const float*)d_in[2];
  const float* beta  = (const float*)d_in[3];
  const float* Wa    = (const float*)d_in[4];
  const float* Wb    = (const float*)d_in[5];
  const float* Wo    = (const float*)d_in[6];
  const float* bo    = (const float*)d_in[7];
  float* out = (float*)d_out;

  char* ws = (char*)d_ws;
  float*          rnm = (float*)(ws);                     // 256 KB
  unsigned short* wo3 = (unsigned short*)(ws + 262144);   // 256 KB
  unsigned short* a_t = (unsigned short*)(ws + 524288);   //   2 MB
  unsigned short* b_t = (unsigned short*)(ws + 2621440);  //   2 MB

  hipFuncSetAttribute((const void*)fused_kernel,
                      hipFuncAttributeMaxDynamicSharedMemorySize, 65536);

  lnp_prep_kernel<<<1408, 256, 0, stream>>>(m, mask, gamma, beta, Wa, Wb, Wo,
                                            rnm, wo3, a_t, b_t);
  fused_kernel<<<dim3(32, 64), 512, 65536, stream>>>(a_t, b_t, wo3, rnm, bo, out);
}